// Round 4
// baseline (76.786 us; speedup 1.0000x reference)
//
#include <hip/hip_runtime.h>

#define B_ 2
#define Q_ 2048
#define K_ 2048
#define H_ 16
#define D_ 64
#define HD_ (H_ * D_)

typedef __bf16 bf16_t;
typedef __attribute__((ext_vector_type(8))) __bf16 bf16x8;
typedef __attribute__((ext_vector_type(4))) __bf16 bf16x4;
typedef __attribute__((ext_vector_type(4))) float f32x4;

// Raw barrier: drains LDS ops only; global register-prefetch stays in flight.
// sched_barrier(0) on both sides pins memory-op motion (rule #18).
#define SBAR() do {                                         \
    __builtin_amdgcn_sched_barrier(0);                      \
    asm volatile("s_waitcnt lgkmcnt(0)" ::: "memory");      \
    __builtin_amdgcn_s_barrier();                           \
    __builtin_amdgcn_sched_barrier(0);                      \
} while (0)

// Swizzled byte offset for a [N][64] bf16 tile (row stride 128 B).
// XOR bits 4-6 with row&7: bijective, keeps 16B granules, kills bank conflicts.
__device__ __forceinline__ int swz(int row, int colByte) {
    return (row * 128 + colByte) ^ ((row & 7) << 4);
}

__global__ __launch_bounds__(256) void attn_fwd_kernel(
    const float* __restrict__ qs, const float* __restrict__ ks,
    const float* __restrict__ vs, const int* __restrict__ valid_lens,
    float* __restrict__ out)
{
    const int qt   = blockIdx.x;   // 128-row q tile
    const int h    = blockIdx.y;
    const int b    = blockIdx.z;
    const int tid  = threadIdx.x;
    const int wave = tid >> 6;     // 0..3, each owns 32 q rows (two 16-row frags)
    const int lane = tid & 63;
    const int l16  = lane & 15;
    const int lhi  = lane >> 4;    // 0..3

    const int valid  = valid_lens[b];
    const int ntiles = (valid + 63) >> 6;   // tiles fully past valid contribute exactly 0

    __shared__ bf16_t k_lds[2][64 * 64];    // [buf][key][d], swizzled
    __shared__ bf16_t v_lds[2][64 * 64];    // [buf][d][key] transposed, swizzled
    __shared__ bf16_t p_buf[4][32 * 64];    // per-wave P tile [q][key], swizzled
    char* const pbase = (char*)&p_buf[wave][0];

    // ---- Q fragments (A-layout: lane = row l16, k-dim d = dh*32+lhi*8+j), scale folded ----
    bf16x8 a_q[2][2];
    #pragma unroll
    for (int f = 0; f < 2; ++f) {
        const int    qrow = qt * 128 + wave * 32 + f * 16 + l16;
        const float* qp   = qs + (((size_t)b * Q_ + qrow) * H_ + h) * D_;
        #pragma unroll
        for (int dh = 0; dh < 2; ++dh) {
            const f32x4* q4 = (const f32x4*)(qp + dh * 32 + lhi * 8);
            f32x4 lo = q4[0], hi = q4[1];
            #pragma unroll
            for (int j = 0; j < 4; ++j) {
                a_q[f][dh][j]     = (bf16_t)(lo[j] * 0.125f);
                a_q[f][dh][4 + j] = (bf16_t)(hi[j] * 0.125f);
            }
        }
    }

    f32x4 o_acc[2][4];
    float m_r[2][4], l_r[2][4];
    #pragma unroll
    for (int f = 0; f < 2; ++f) {
        #pragma unroll
        for (int t = 0; t < 4; ++t) o_acc[f][t] = (f32x4){0.f, 0.f, 0.f, 0.f};
        #pragma unroll
        for (int r = 0; r < 4; ++r) { m_r[f][r] = -1e30f; l_r[f][r] = 0.f; }
    }

    const float* kb = ks + ((size_t)b * K_ * H_ + h) * D_;
    const float* vg = vs + ((size_t)b * K_ * H_ + h) * D_;

    // staging maps
    const int krow  = tid >> 2;          // 0..63 (key)
    const int kcolf = (tid & 3) * 16;    // float col base
    const int vr    = (tid & 15) * 4;    // key base (4 rows)
    const int vc    = (tid >> 4) * 4;    // d base (4 cols)

    f32x4 kreg[4], vreg[4];   // in-flight next tile (lives across the barrier!)

    auto issue_loads = [&](int kt) {
        const float* ksrc = kb + (size_t)(kt * 64 + krow) * HD_ + kcolf;
        #pragma unroll
        for (int i = 0; i < 4; ++i) kreg[i] = ((const f32x4*)ksrc)[i];
        #pragma unroll
        for (int i = 0; i < 4; ++i)
            vreg[i] = *(const f32x4*)(vg + (size_t)(kt * 64 + vr + i) * HD_ + vc);
    };

    auto write_tile = [&](int bi) {
        char* kdst = (char*)&k_lds[bi][0];
        char* vdst = (char*)&v_lds[bi][0];
        bf16x8 lo, hi;
        #pragma unroll
        for (int j = 0; j < 4; ++j) {
            lo[j] = (bf16_t)kreg[0][j]; lo[4 + j] = (bf16_t)kreg[1][j];
            hi[j] = (bf16_t)kreg[2][j]; hi[4 + j] = (bf16_t)kreg[3][j];
        }
        *(bf16x8*)(kdst + swz(krow, kcolf * 2))      = lo;
        *(bf16x8*)(kdst + swz(krow, kcolf * 2 + 16)) = hi;
        #pragma unroll
        for (int j = 0; j < 4; ++j) {
            bf16x4 w;
            w[0] = (bf16_t)vreg[0][j]; w[1] = (bf16_t)vreg[1][j];
            w[2] = (bf16_t)vreg[2][j]; w[3] = (bf16_t)vreg[3][j];
            *(bf16x4*)(vdst + swz(vc + j, vr * 2)) = w;
        }
    };

    // prologue: tile 0 straight to LDS
    issue_loads(0);
    write_tile(0);
    int cur = 0;

    for (int kt = 0; kt < ntiles; ++kt) {
        const bool more = (kt + 1 < ntiles);
        if (more) issue_loads(kt + 1);   // stays in flight across SBAR (no vmcnt drain)
        SBAR();                          // buf[cur] ds_writes visible; readers of buf[cur^1] done

        char* const kbase = (char*)&k_lds[cur][0];
        char* const vbase = (char*)&v_lds[cur][0];

        // ---- S = (Q*scale) K^T : shared K-frag reads feed both q sub-tiles ----
        f32x4 s[2][4];
        #pragma unroll
        for (int f = 0; f < 2; ++f)
            #pragma unroll
            for (int n = 0; n < 4; ++n) s[f][n] = (f32x4){0.f, 0.f, 0.f, 0.f};
        #pragma unroll
        for (int n = 0; n < 4; ++n) {
            #pragma unroll
            for (int dh = 0; dh < 2; ++dh) {
                bf16x8 bk = *(const bf16x8*)(kbase + swz(n * 16 + l16, dh * 64 + lhi * 16));
                s[0][n] = __builtin_amdgcn_mfma_f32_16x16x32_bf16(a_q[0][dh], bk, s[0][n], 0, 0, 0);
                s[1][n] = __builtin_amdgcn_mfma_f32_16x16x32_bf16(a_q[1][dh], bk, s[1][n], 0, 0, 0);
            }
        }

        // ---- mask only on the boundary tile (uniform branch) ----
        if (kt * 64 + 64 > valid) {
            #pragma unroll
            for (int n = 0; n < 4; ++n) {
                const bool ok = (kt * 64 + n * 16 + l16) < valid;
                #pragma unroll
                for (int f = 0; f < 2; ++f)
                    #pragma unroll
                    for (int r = 0; r < 4; ++r)
                        if (!ok) s[f][n][r] = -1e30f;
            }
        }

        // ---- online softmax (rows on 16-lane groups) + P to wave-private LDS ----
        #pragma unroll
        for (int f = 0; f < 2; ++f) {
            #pragma unroll
            for (int r = 0; r < 4; ++r) {
                float rm = fmaxf(fmaxf(s[f][0][r], s[f][1][r]), fmaxf(s[f][2][r], s[f][3][r]));
                #pragma unroll
                for (int off = 1; off < 16; off <<= 1)
                    rm = fmaxf(rm, __shfl_xor(rm, off, 64));
                const float mnew  = fmaxf(m_r[f][r], rm);
                const float alpha = __expf(m_r[f][r] - mnew);
                float e[4], psum = 0.f;
                #pragma unroll
                for (int n = 0; n < 4; ++n) {
                    e[n] = __expf(s[f][n][r] - mnew);
                    psum += e[n];
                }
                #pragma unroll
                for (int off = 1; off < 16; off <<= 1)
                    psum += __shfl_xor(psum, off, 64);
                l_r[f][r] = l_r[f][r] * alpha + psum;
                m_r[f][r] = mnew;
                #pragma unroll
                for (int t = 0; t < 4; ++t) o_acc[f][t][r] *= alpha;
                #pragma unroll
                for (int n = 0; n < 4; ++n)
                    *(bf16_t*)(pbase + swz(f * 16 + lhi * 4 + r, (n * 16 + l16) * 2)) = (bf16_t)e[n];
            }
        }

        bf16x8 pa[2][2];
        #pragma unroll
        for (int f = 0; f < 2; ++f)
            #pragma unroll
            for (int kk = 0; kk < 2; ++kk)
                pa[f][kk] = *(const bf16x8*)(pbase + swz(f * 16 + l16, kk * 64 + lhi * 16));

        // ---- PV: shared V-frag reads feed both q sub-tiles ----
        #pragma unroll
        for (int t = 0; t < 4; ++t) {
            #pragma unroll
            for (int kk = 0; kk < 2; ++kk) {
                bf16x8 vb = *(const bf16x8*)(vbase + swz(t * 16 + l16, kk * 64 + lhi * 16));
                o_acc[0][t] = __builtin_amdgcn_mfma_f32_16x16x32_bf16(pa[0][kk], vb, o_acc[0][t], 0, 0, 0);
                o_acc[1][t] = __builtin_amdgcn_mfma_f32_16x16x32_bf16(pa[1][kk], vb, o_acc[1][t], 0, 0, 0);
            }
        }

        // regs -> LDS for next tile; vmcnt paid HERE (after full compute phase)
        if (more) write_tile(cur ^ 1);
        cur ^= 1;
    }

    // ---- epilogue: divide by l, store fp32 ----
    #pragma unroll
    for (int f = 0; f < 2; ++f) {
        float* op = out + (((size_t)b * Q_ + qt * 128 + wave * 32 + f * 16) * H_ + h) * D_;
        #pragma unroll
        for (int r = 0; r < 4; ++r) {
            const int   row = lhi * 4 + r;
            const float inv = 1.f / l_r[f][r];
            #pragma unroll
            for (int t = 0; t < 4; ++t)
                op[(size_t)row * HD_ + t * 16 + l16] = o_acc[f][t][r] * inv;
        }
    }
}

extern "C" void kernel_launch(void* const* d_in, const int* in_sizes, int n_in,
                              void* d_out, int out_size, void* d_ws, size_t ws_size,
                              hipStream_t stream) {
    const float* qs = (const float*)d_in[0];
    const float* ks = (const float*)d_in[1];
    const float* vs = (const float*)d_in[2];
    const int*   vl = (const int*)d_in[3];
    float*       out = (float*)d_out;
    dim3 grid(Q_ / 128, H_, B_);
    attn_fwd_kernel<<<grid, 256, 0, stream>>>(qs, ks, vs, vl, out);
}

// Round 5
// 56.429 us; speedup vs baseline: 1.3608x; 1.3608x over previous
//
#include <hip/hip_runtime.h>

#define B_ 2
#define Q_ 2048
#define K_ 2048
#define H_ 16
#define D_ 64
#define HD_ (H_ * D_)

typedef __bf16 bf16_t;
typedef __attribute__((ext_vector_type(8))) __bf16 bf16x8;
typedef __attribute__((ext_vector_type(4))) __bf16 bf16x4;
typedef __attribute__((ext_vector_type(4))) float f32x4;

// Raw barrier: drains LDS ops only; global register-prefetch stays in flight.
#define SBAR() do {                                         \
    __builtin_amdgcn_sched_barrier(0);                      \
    asm volatile("s_waitcnt lgkmcnt(0)" ::: "memory");      \
    __builtin_amdgcn_s_barrier();                           \
    __builtin_amdgcn_sched_barrier(0);                      \
} while (0)

// Swizzled byte offset for a [N][64] bf16 tile (row stride 128 B).
// XOR bits 4-6 with row&7: bijective, keeps 16B granules, kills bank conflicts.
__device__ __forceinline__ int swz(int row, int colByte) {
    return (row * 128 + colByte) ^ ((row & 7) << 4);
}

__global__ __launch_bounds__(512, 4) void attn_fwd_kernel(
    const float* __restrict__ qs, const float* __restrict__ ks,
    const float* __restrict__ vs, const int* __restrict__ valid_lens,
    float* __restrict__ out)
{
    const int qt   = blockIdx.x;   // 128-row q tile
    const int h    = blockIdx.y;
    const int b    = blockIdx.z;
    const int tid  = threadIdx.x;
    const int wave = tid >> 6;     // 0..7, each owns 16 q rows
    const int lane = tid & 63;
    const int l16  = lane & 15;
    const int lhi  = lane >> 4;    // 0..3

    const int valid  = valid_lens[b];
    const int ntiles = (valid + 63) >> 6;   // tiles fully past valid contribute exactly 0

    __shared__ bf16_t k_lds[2][64 * 64];    // [buf][key][d], swizzled
    __shared__ bf16_t v_lds[2][64 * 64];    // [buf][d][key] transposed, swizzled
    __shared__ bf16_t p_buf[8][16 * 64];    // per-wave P tile [q][key], swizzled
    char* const pbase = (char*)&p_buf[wave][0];

    // ---- Q fragment (A-layout: lane = row l16, k-dim d = dh*32+lhi*8+j), scale folded ----
    const int    qrow = qt * 128 + wave * 16 + l16;
    const float* qp   = qs + (((size_t)b * Q_ + qrow) * H_ + h) * D_;
    bf16x8 a_q[2];
    #pragma unroll
    for (int dh = 0; dh < 2; ++dh) {
        const f32x4* q4 = (const f32x4*)(qp + dh * 32 + lhi * 8);
        f32x4 lo = q4[0], hi = q4[1];
        #pragma unroll
        for (int j = 0; j < 4; ++j) {
            a_q[dh][j]     = (bf16_t)(lo[j] * 0.125f);
            a_q[dh][4 + j] = (bf16_t)(hi[j] * 0.125f);
        }
    }

    f32x4 o_acc[4];
    #pragma unroll
    for (int t = 0; t < 4; ++t) o_acc[t] = (f32x4){0.f, 0.f, 0.f, 0.f};
    float m_r[4], l_r[4];
    #pragma unroll
    for (int r = 0; r < 4; ++r) { m_r[r] = -1e30f; l_r[r] = 0.f; }

    const float* kb = ks + ((size_t)b * K_ * H_ + h) * D_;
    const float* vg = vs + ((size_t)b * K_ * H_ + h) * D_;

    // staging role split (wave-uniform): waves 0-3 stage K, waves 4-7 stage V
    const bool kRole = (tid < 256);
    const int  st    = kRole ? tid : (tid - 256);   // 0..255
    const int  krow  = st >> 2;                     // 0..63 (key)
    const int  kcolf = (st & 3) * 16;               // float col base
    const int  vr    = (st & 15) * 4;               // key base (4 rows)
    const int  vc    = (st >> 4) * 4;               // d base (4 cols)

    f32x4 reg[4];   // in-flight next tile (lives across the barrier)

    auto issue_loads = [&](int kt) {
        if (kRole) {
            const float* ksrc = kb + (size_t)(kt * 64 + krow) * HD_ + kcolf;
            #pragma unroll
            for (int i = 0; i < 4; ++i) reg[i] = ((const f32x4*)ksrc)[i];
        } else {
            #pragma unroll
            for (int i = 0; i < 4; ++i)
                reg[i] = *(const f32x4*)(vg + (size_t)(kt * 64 + vr + i) * HD_ + vc);
        }
    };

    auto write_tile = [&](int bi) {
        if (kRole) {
            char* kdst = (char*)&k_lds[bi][0];
            bf16x8 lo, hi;
            #pragma unroll
            for (int j = 0; j < 4; ++j) {
                lo[j] = (bf16_t)reg[0][j]; lo[4 + j] = (bf16_t)reg[1][j];
                hi[j] = (bf16_t)reg[2][j]; hi[4 + j] = (bf16_t)reg[3][j];
            }
            *(bf16x8*)(kdst + swz(krow, kcolf * 2))      = lo;
            *(bf16x8*)(kdst + swz(krow, kcolf * 2 + 16)) = hi;
        } else {
            char* vdst = (char*)&v_lds[bi][0];
            #pragma unroll
            for (int j = 0; j < 4; ++j) {
                bf16x4 w;
                w[0] = (bf16_t)reg[0][j]; w[1] = (bf16_t)reg[1][j];
                w[2] = (bf16_t)reg[2][j]; w[3] = (bf16_t)reg[3][j];
                *(bf16x4*)(vdst + swz(vc + j, vr * 2)) = w;
            }
        }
    };

    // prologue: tile 0 straight to LDS
    issue_loads(0);
    write_tile(0);
    int cur = 0;

    for (int kt = 0; kt < ntiles; ++kt) {
        const bool more = (kt + 1 < ntiles);
        if (more) issue_loads(kt + 1);   // stays in flight across SBAR (no vmcnt drain)
        SBAR();                          // buf[cur] ds_writes visible; readers of buf[cur^1] done

        char* const kbase = (char*)&k_lds[cur][0];
        char* const vbase = (char*)&v_lds[cur][0];

        // ---- S = (Q*scale) K^T : four 16-key n-tiles, d-dim 64 in 2 halves ----
        f32x4 s[4];
        #pragma unroll
        for (int n = 0; n < 4; ++n) s[n] = (f32x4){0.f, 0.f, 0.f, 0.f};
        #pragma unroll
        for (int n = 0; n < 4; ++n) {
            #pragma unroll
            for (int dh = 0; dh < 2; ++dh) {
                bf16x8 bk = *(const bf16x8*)(kbase + swz(n * 16 + l16, dh * 64 + lhi * 16));
                s[n] = __builtin_amdgcn_mfma_f32_16x16x32_bf16(a_q[dh], bk, s[n], 0, 0, 0);
            }
        }

        // ---- mask only on the boundary tile (uniform branch) ----
        if (kt * 64 + 64 > valid) {
            #pragma unroll
            for (int n = 0; n < 4; ++n) {
                const bool ok = (kt * 64 + n * 16 + l16) < valid;
                #pragma unroll
                for (int r = 0; r < 4; ++r)
                    if (!ok) s[n][r] = -1e30f;
            }
        }

        // ---- online softmax (rows on 16-lane groups, row = lhi*4 + r) ----
        #pragma unroll
        for (int r = 0; r < 4; ++r) {
            float rm = fmaxf(fmaxf(s[0][r], s[1][r]), fmaxf(s[2][r], s[3][r]));
            #pragma unroll
            for (int off = 1; off < 16; off <<= 1)
                rm = fmaxf(rm, __shfl_xor(rm, off, 64));
            const float mnew  = fmaxf(m_r[r], rm);
            const float alpha = __expf(m_r[r] - mnew);
            float e[4], psum = 0.f;
            #pragma unroll
            for (int n = 0; n < 4; ++n) {
                e[n] = __expf(s[n][r] - mnew);
                psum += e[n];
            }
            #pragma unroll
            for (int off = 1; off < 16; off <<= 1)
                psum += __shfl_xor(psum, off, 64);
            l_r[r] = l_r[r] * alpha + psum;
            m_r[r] = mnew;
            #pragma unroll
            for (int t = 0; t < 4; ++t) o_acc[t][r] *= alpha;
            #pragma unroll
            for (int n = 0; n < 4; ++n)
                *(bf16_t*)(pbase + swz(lhi * 4 + r, (n * 16 + l16) * 2)) = (bf16_t)e[n];
        }

        bf16x8 pa[2];
        #pragma unroll
        for (int kk = 0; kk < 2; ++kk)
            pa[kk] = *(const bf16x8*)(pbase + swz(l16, kk * 64 + lhi * 16));

        // ---- PV: O += P * V  (B-fragments from transposed V) ----
        #pragma unroll
        for (int t = 0; t < 4; ++t) {
            #pragma unroll
            for (int kk = 0; kk < 2; ++kk) {
                bf16x8 vb = *(const bf16x8*)(vbase + swz(t * 16 + l16, kk * 64 + lhi * 16));
                o_acc[t] = __builtin_amdgcn_mfma_f32_16x16x32_bf16(pa[kk], vb, o_acc[t], 0, 0, 0);
            }
        }

        // regs -> LDS for next tile; vmcnt paid HERE (after full compute phase)
        if (more) write_tile(cur ^ 1);
        cur ^= 1;
    }

    // ---- epilogue: divide by l, store fp32 ----
    float* op = out + (((size_t)b * Q_ + qt * 128 + wave * 16) * H_ + h) * D_;
    #pragma unroll
    for (int r = 0; r < 4; ++r) {
        const int   row = lhi * 4 + r;
        const float inv = 1.f / l_r[r];
        #pragma unroll
        for (int t = 0; t < 4; ++t)
            op[(size_t)row * HD_ + t * 16 + l16] = o_acc[t][r] * inv;
    }
}

extern "C" void kernel_launch(void* const* d_in, const int* in_sizes, int n_in,
                              void* d_out, int out_size, void* d_ws, size_t ws_size,
                              hipStream_t stream) {
    const float* qs = (const float*)d_in[0];
    const float* ks = (const float*)d_in[1];
    const float* vs = (const float*)d_in[2];
    const int*   vl = (const int*)d_in[3];
    float*       out = (float*)d_out;
    dim3 grid(Q_ / 128, H_, B_);
    attn_fwd_kernel<<<grid, 512, 0, stream>>>(qs, ks, vs, vl, out);
}

// Round 6
// 41.442 us; speedup vs baseline: 1.8528x; 1.3616x over previous
//
#include <hip/hip_runtime.h>

#define B_ 2
#define Q_ 2048
#define K_ 2048
#define H_ 16
#define D_ 64
#define HD_ (H_ * D_)

// Q pre-scale: (1/sqrt(64)) * log2(e)  -> scores come out in log2 units,
// so softmax uses raw v_exp_f32 (2^x) with no per-element multiply.
#define QSCALE 0.18033688011112042f
#define DEFER_THR 10.0f   // log2-units; P bounded by 2^10, fine in bf16/f32

typedef __bf16 bf16_t;
typedef __attribute__((ext_vector_type(8))) __bf16 bf16x8;
typedef __attribute__((ext_vector_type(4))) __bf16 bf16x4;
typedef __attribute__((ext_vector_type(4))) float f32x4;

// Raw barrier: drains LDS ops only; global register-prefetch stays in flight.
#define SBAR() do {                                         \
    __builtin_amdgcn_sched_barrier(0);                      \
    asm volatile("s_waitcnt lgkmcnt(0)" ::: "memory");      \
    __builtin_amdgcn_s_barrier();                           \
    __builtin_amdgcn_sched_barrier(0);                      \
} while (0)

// Swizzled byte offset for a [N][64] bf16 tile (row stride 128 B).
// XOR bits 4-6 with row&7: bijective, keeps 16B granules, kills bank conflicts.
__device__ __forceinline__ int swz(int row, int colByte) {
    return (row * 128 + colByte) ^ ((row & 7) << 4);
}

__global__ __launch_bounds__(512, 4) void attn_fwd_kernel(
    const float* __restrict__ qs, const float* __restrict__ ks,
    const float* __restrict__ vs, const int* __restrict__ valid_lens,
    float* __restrict__ out)
{
    const int qt   = blockIdx.x;   // 128-row q tile
    const int h    = blockIdx.y;
    const int b    = blockIdx.z;
    const int tid  = threadIdx.x;
    const int wave = tid >> 6;     // 0..7, each owns 16 q rows
    const int lane = tid & 63;
    const int l16  = lane & 15;
    const int lhi  = lane >> 4;    // 0..3

    const int valid  = valid_lens[b];
    const int ntiles = (valid + 63) >> 6;   // tiles fully past valid contribute exactly 0

    __shared__ bf16_t k_lds[2][64 * 64];    // [buf][key][d], swizzled
    __shared__ bf16_t v_lds[2][64 * 64];    // [buf][d][key] transposed, swizzled
    __shared__ bf16_t p_buf[8][16 * 64];    // per-wave P tile [q][key], swizzled
    char* const pbase = (char*)&p_buf[wave][0];

    // ---- Q fragment (A-layout: lane = row l16, k-dim d = dh*32+lhi*8+j), scale folded ----
    const int    qrow = qt * 128 + wave * 16 + l16;
    const float* qp   = qs + (((size_t)b * Q_ + qrow) * H_ + h) * D_;
    bf16x8 a_q[2];
    #pragma unroll
    for (int dh = 0; dh < 2; ++dh) {
        const f32x4* q4 = (const f32x4*)(qp + dh * 32 + lhi * 8);
        f32x4 lo = q4[0], hi = q4[1];
        #pragma unroll
        for (int j = 0; j < 4; ++j) {
            a_q[dh][j]     = (bf16_t)(lo[j] * QSCALE);
            a_q[dh][4 + j] = (bf16_t)(hi[j] * QSCALE);
        }
    }

    f32x4 o_acc[4];
    #pragma unroll
    for (int t = 0; t < 4; ++t) o_acc[t] = (f32x4){0.f, 0.f, 0.f, 0.f};
    float m_r[4], l_part[4];   // l_part: per-LANE partial sum (16-lane reduce deferred to epilogue)
    #pragma unroll
    for (int r = 0; r < 4; ++r) { m_r[r] = -1e30f; l_part[r] = 0.f; }

    const float* kb = ks + ((size_t)b * K_ * H_ + h) * D_;
    const float* vg = vs + ((size_t)b * K_ * H_ + h) * D_;

    // staging role split (wave-uniform): waves 0-3 stage K, waves 4-7 stage V
    const bool kRole = (tid < 256);
    const int  st    = kRole ? tid : (tid - 256);   // 0..255
    const int  krow  = st >> 2;                     // 0..63 (key)
    const int  kcolf = (st & 3) * 16;               // float col base
    const int  vr    = (st & 15) * 4;               // key base (4 rows)
    const int  vc    = (st >> 4) * 4;               // d base (4 cols)

    f32x4 reg[4];   // in-flight next tile (lives across the barrier)

    auto issue_loads = [&](int kt) {
        if (kRole) {
            const float* ksrc = kb + (size_t)(kt * 64 + krow) * HD_ + kcolf;
            #pragma unroll
            for (int i = 0; i < 4; ++i) reg[i] = ((const f32x4*)ksrc)[i];
        } else {
            #pragma unroll
            for (int i = 0; i < 4; ++i)
                reg[i] = *(const f32x4*)(vg + (size_t)(kt * 64 + vr + i) * HD_ + vc);
        }
    };

    auto write_tile = [&](int bi) {
        if (kRole) {
            char* kdst = (char*)&k_lds[bi][0];
            bf16x8 lo, hi;
            #pragma unroll
            for (int j = 0; j < 4; ++j) {
                lo[j] = (bf16_t)reg[0][j]; lo[4 + j] = (bf16_t)reg[1][j];
                hi[j] = (bf16_t)reg[2][j]; hi[4 + j] = (bf16_t)reg[3][j];
            }
            *(bf16x8*)(kdst + swz(krow, kcolf * 2))      = lo;
            *(bf16x8*)(kdst + swz(krow, kcolf * 2 + 16)) = hi;
        } else {
            char* vdst = (char*)&v_lds[bi][0];
            #pragma unroll
            for (int j = 0; j < 4; ++j) {
                bf16x4 w;
                w[0] = (bf16_t)reg[0][j]; w[1] = (bf16_t)reg[1][j];
                w[2] = (bf16_t)reg[2][j]; w[3] = (bf16_t)reg[3][j];
                *(bf16x4*)(vdst + swz(vc + j, vr * 2)) = w;
            }
        }
    };

    // prologue: tile 0 straight to LDS
    issue_loads(0);
    write_tile(0);
    int cur = 0;

    for (int kt = 0; kt < ntiles; ++kt) {
        const bool more = (kt + 1 < ntiles);
        if (more) issue_loads(kt + 1);   // stays in flight across SBAR (no vmcnt drain)
        SBAR();                          // buf[cur] ds_writes visible; readers of buf[cur^1] done

        char* const kbase = (char*)&k_lds[cur][0];
        char* const vbase = (char*)&v_lds[cur][0];

        // ---- S = Q K^T (log2-scaled): four 16-key n-tiles, d-dim 64 in 2 halves ----
        f32x4 s[4];
        #pragma unroll
        for (int n = 0; n < 4; ++n) s[n] = (f32x4){0.f, 0.f, 0.f, 0.f};
        __builtin_amdgcn_s_setprio(1);
        #pragma unroll
        for (int n = 0; n < 4; ++n) {
            #pragma unroll
            for (int dh = 0; dh < 2; ++dh) {
                bf16x8 bk = *(const bf16x8*)(kbase + swz(n * 16 + l16, dh * 64 + lhi * 16));
                s[n] = __builtin_amdgcn_mfma_f32_16x16x32_bf16(a_q[dh], bk, s[n], 0, 0, 0);
            }
        }
        __builtin_amdgcn_s_setprio(0);

        // ---- mask only on the boundary tile (uniform branch) ----
        if (kt * 64 + 64 > valid) {
            #pragma unroll
            for (int n = 0; n < 4; ++n) {
                const bool ok = (kt * 64 + n * 16 + l16) < valid;
                #pragma unroll
                for (int r = 0; r < 4; ++r)
                    if (!ok) s[n][r] = -1e30f;
            }
        }

        // ---- deferred-max online softmax ----
        // lane-local row max (exact gate: rm>m+T iff some lane's lm>m+T)
        float lm[4];
        bool need = false;
        #pragma unroll
        for (int r = 0; r < 4; ++r) {
            lm[r] = fmaxf(fmaxf(s[0][r], s[1][r]), fmaxf(s[2][r], s[3][r]));
            need = need || (lm[r] > m_r[r] + DEFER_THR);
        }
        if (__any(need)) {   // wave-uniform update path (rare)
            #pragma unroll
            for (int r = 0; r < 4; ++r) {
                float rm = lm[r];
                #pragma unroll
                for (int off = 1; off < 16; off <<= 1)
                    rm = fmaxf(rm, __shfl_xor(rm, off, 64));
                const float mnew = fmaxf(m_r[r], rm);
                const float alpha = __builtin_amdgcn_exp2f(m_r[r] - mnew);
                m_r[r] = mnew;
                l_part[r] *= alpha;
                #pragma unroll
                for (int t = 0; t < 4; ++t) o_acc[t][r] *= alpha;
            }
        }
        // P = 2^(s - m), lane-partial l accumulation, P -> wave-private LDS
        #pragma unroll
        for (int r = 0; r < 4; ++r) {
            float psum = 0.f;
            #pragma unroll
            for (int n = 0; n < 4; ++n) {
                const float e = __builtin_amdgcn_exp2f(s[n][r] - m_r[r]);
                psum += e;
                *(bf16_t*)(pbase + swz(lhi * 4 + r, (n * 16 + l16) * 2)) = (bf16_t)e;
            }
            l_part[r] += psum;
        }

        bf16x8 pa[2];
        #pragma unroll
        for (int kk = 0; kk < 2; ++kk)
            pa[kk] = *(const bf16x8*)(pbase + swz(l16, kk * 64 + lhi * 16));

        // ---- PV: O += P * V  (B-fragments from transposed V) ----
        __builtin_amdgcn_s_setprio(1);
        #pragma unroll
        for (int t = 0; t < 4; ++t) {
            #pragma unroll
            for (int kk = 0; kk < 2; ++kk) {
                bf16x8 vb = *(const bf16x8*)(vbase + swz(t * 16 + l16, kk * 64 + lhi * 16));
                o_acc[t] = __builtin_amdgcn_mfma_f32_16x16x32_bf16(pa[kk], vb, o_acc[t], 0, 0, 0);
            }
        }
        __builtin_amdgcn_s_setprio(0);

        // regs -> LDS for next tile; vmcnt paid HERE (after full compute phase)
        if (more) write_tile(cur ^ 1);
        cur ^= 1;
    }

    // ---- epilogue: finish the deferred 16-lane l reduction, divide, store fp32 ----
    float* op = out + (((size_t)b * Q_ + qt * 128 + wave * 16) * H_ + h) * D_;
    #pragma unroll
    for (int r = 0; r < 4; ++r) {
        float l = l_part[r];
        #pragma unroll
        for (int off = 1; off < 16; off <<= 1)
            l += __shfl_xor(l, off, 64);
        const int   row = lhi * 4 + r;
        const float inv = 1.f / l;
        #pragma unroll
        for (int t = 0; t < 4; ++t)
            op[(size_t)row * HD_ + t * 16 + l16] = o_acc[t][r] * inv;
    }
}

extern "C" void kernel_launch(void* const* d_in, const int* in_sizes, int n_in,
                              void* d_out, int out_size, void* d_ws, size_t ws_size,
                              hipStream_t stream) {
    const float* qs = (const float*)d_in[0];
    const float* ks = (const float*)d_in[1];
    const float* vs = (const float*)d_in[2];
    const int*   vl = (const int*)d_in[3];
    float*       out = (float*)d_out;
    dim3 grid(Q_ / 128, H_, B_);
    attn_fwd_kernel<<<grid, 512, 0, stream>>>(qs, ks, vs, vl, out);
}

// Round 7
// 39.114 us; speedup vs baseline: 1.9631x; 1.0595x over previous
//
#include <hip/hip_runtime.h>

#define B_ 2
#define Q_ 2048
#define K_ 2048
#define H_ 16
#define D_ 64
#define HD_ (H_ * D_)

// Q pre-scale: (1/sqrt(64)) * log2(e)  -> scores in log2 units; softmax uses
// raw v_exp_f32 (2^x) with no per-element multiply.
#define QSCALE 0.18033688011112042f
#define DEFER_THR 10.0f   // log2-units; P bounded by 2^10, fine in bf16/f32

typedef __bf16 bf16_t;
typedef __attribute__((ext_vector_type(8))) __bf16 bf16x8;
typedef __attribute__((ext_vector_type(4))) __bf16 bf16x4;
typedef __attribute__((ext_vector_type(4))) float f32x4;

// Raw barrier: drains LDS ops only; global register-prefetch stays in flight.
#define SBAR() do {                                         \
    __builtin_amdgcn_sched_barrier(0);                      \
    asm volatile("s_waitcnt lgkmcnt(0)" ::: "memory");      \
    __builtin_amdgcn_s_barrier();                           \
    __builtin_amdgcn_sched_barrier(0);                      \
} while (0)

// Swizzled byte offset for a [N][64] bf16 tile (row stride 128 B).
// XOR bits 4-6 with row&7: bijective, keeps 16B granules, kills bank conflicts.
__device__ __forceinline__ int swz(int row, int colByte) {
    return (row * 128 + colByte) ^ ((row & 7) << 4);
}

__global__ __launch_bounds__(512, 4) void attn_fwd_kernel(
    const float* __restrict__ qs, const float* __restrict__ ks,
    const float* __restrict__ vs, const int* __restrict__ valid_lens,
    float* __restrict__ out)
{
    const int qt   = blockIdx.x;   // 128-row q tile
    const int h    = blockIdx.y;
    const int b    = blockIdx.z;
    const int tid  = threadIdx.x;
    const int wave = tid >> 6;     // 0..7, each owns 16 q rows
    const int lane = tid & 63;
    const int l16  = lane & 15;
    const int lhi  = lane >> 4;    // 0..3

    const int valid  = valid_lens[b];
    const int ntiles = (valid + 63) >> 6;   // tiles fully past valid contribute exactly 0

    __shared__ bf16_t k_lds[2][64 * 64];    // [buf][key][d], swizzled
    __shared__ bf16_t v_lds[2][64 * 64];    // [buf][d][key] transposed, swizzled
    __shared__ bf16_t p_buf[8][16 * 64];    // per-wave P tile [q][key], swizzled
    char* const pbase = (char*)&p_buf[wave][0];

    // ---- Q fragment (lane = row l16, k-dim d = dh*32+lhi*8+j), scale folded.
    // Used as the B-operand of the swapped QK^T (same register layout).
    const int    qrow = qt * 128 + wave * 16 + l16;
    const float* qp   = qs + (((size_t)b * Q_ + qrow) * H_ + h) * D_;
    bf16x8 a_q[2];
    #pragma unroll
    for (int dh = 0; dh < 2; ++dh) {
        const f32x4* q4 = (const f32x4*)(qp + dh * 32 + lhi * 8);
        f32x4 lo = q4[0], hi = q4[1];
        #pragma unroll
        for (int j = 0; j < 4; ++j) {
            a_q[dh][j]     = (bf16_t)(lo[j] * QSCALE);
            a_q[dh][4 + j] = (bf16_t)(hi[j] * QSCALE);
        }
    }

    // O accumulator: C-layout of swapped PV -> lane holds q-row = l16,
    // d = t*16 + lhi*4 + r. Softmax state is per-lane scalars.
    f32x4 o_acc[4];
    #pragma unroll
    for (int t = 0; t < 4; ++t) o_acc[t] = (f32x4){0.f, 0.f, 0.f, 0.f};
    float m_r = -1e30f, l_part = 0.f;

    const float* kb = ks + ((size_t)b * K_ * H_ + h) * D_;
    const float* vg = vs + ((size_t)b * K_ * H_ + h) * D_;

    // staging role split (wave-uniform): waves 0-3 stage K, waves 4-7 stage V
    const bool kRole = (tid < 256);
    const int  st    = kRole ? tid : (tid - 256);   // 0..255
    const int  krow  = st >> 2;                     // 0..63 (key)
    const int  kcolf = (st & 3) * 16;               // float col base
    const int  vr    = (st & 15) * 4;               // key base (4 rows)
    const int  vc    = (st >> 4) * 4;               // d base (4 cols)

    f32x4 reg[4];   // in-flight next tile (lives across the barrier)

    auto issue_loads = [&](int kt) {
        if (kRole) {
            const float* ksrc = kb + (size_t)(kt * 64 + krow) * HD_ + kcolf;
            #pragma unroll
            for (int i = 0; i < 4; ++i) reg[i] = ((const f32x4*)ksrc)[i];
        } else {
            #pragma unroll
            for (int i = 0; i < 4; ++i)
                reg[i] = *(const f32x4*)(vg + (size_t)(kt * 64 + vr + i) * HD_ + vc);
        }
    };

    auto write_tile = [&](int bi) {
        if (kRole) {
            char* kdst = (char*)&k_lds[bi][0];
            bf16x8 lo, hi;
            #pragma unroll
            for (int j = 0; j < 4; ++j) {
                lo[j] = (bf16_t)reg[0][j]; lo[4 + j] = (bf16_t)reg[1][j];
                hi[j] = (bf16_t)reg[2][j]; hi[4 + j] = (bf16_t)reg[3][j];
            }
            *(bf16x8*)(kdst + swz(krow, kcolf * 2))      = lo;
            *(bf16x8*)(kdst + swz(krow, kcolf * 2 + 16)) = hi;
        } else {
            char* vdst = (char*)&v_lds[bi][0];
            #pragma unroll
            for (int j = 0; j < 4; ++j) {
                bf16x4 w;
                w[0] = (bf16_t)reg[0][j]; w[1] = (bf16_t)reg[1][j];
                w[2] = (bf16_t)reg[2][j]; w[3] = (bf16_t)reg[3][j];
                *(bf16x4*)(vdst + swz(vc + j, vr * 2)) = w;
            }
        }
    };

    // prologue: tile 0 straight to LDS
    issue_loads(0);
    write_tile(0);
    int cur = 0;

    for (int kt = 0; kt < ntiles; ++kt) {
        const bool more = (kt + 1 < ntiles);
        if (more) issue_loads(kt + 1);   // stays in flight across SBAR (no vmcnt drain)
        SBAR();                          // buf[cur] ds_writes visible; readers of buf[cur^1] done

        char* const kbase = (char*)&k_lds[cur][0];
        char* const vbase = (char*)&v_lds[cur][0];

        // ---- S^T = K Q^T (swapped operands): lane holds q-row l16,
        // keys n*16 + lhi*4 + r across s[n][r]. Same LDS reads as before.
        f32x4 s[4];
        #pragma unroll
        for (int n = 0; n < 4; ++n) s[n] = (f32x4){0.f, 0.f, 0.f, 0.f};
        __builtin_amdgcn_s_setprio(1);
        #pragma unroll
        for (int n = 0; n < 4; ++n) {
            #pragma unroll
            for (int dh = 0; dh < 2; ++dh) {
                bf16x8 ak = *(const bf16x8*)(kbase + swz(n * 16 + l16, dh * 64 + lhi * 16));
                s[n] = __builtin_amdgcn_mfma_f32_16x16x32_bf16(ak, a_q[dh], s[n], 0, 0, 0);
            }
        }
        __builtin_amdgcn_s_setprio(0);

        // ---- mask only on the boundary tile (uniform branch) ----
        if (kt * 64 + 64 > valid) {
            #pragma unroll
            for (int n = 0; n < 4; ++n) {
                const int kbase_i = kt * 64 + n * 16 + lhi * 4;
                #pragma unroll
                for (int r = 0; r < 4; ++r)
                    if (kbase_i + r >= valid) s[n][r] = -1e30f;
            }
        }

        // ---- deferred-max online softmax, all state lane-local ----
        float lm = s[0][0];
        #pragma unroll
        for (int n = 0; n < 4; ++n)
            #pragma unroll
            for (int r = 0; r < 4; ++r) lm = fmaxf(lm, s[n][r]);
        if (__any(lm > m_r + DEFER_THR)) {   // rare, wave-uniform update
            float rm = fmaxf(lm, __shfl_xor(lm, 16, 64));
            rm = fmaxf(rm, __shfl_xor(rm, 32, 64));
            const float mnew  = fmaxf(m_r, rm);
            const float alpha = __builtin_amdgcn_exp2f(m_r - mnew);
            m_r = mnew;
            l_part *= alpha;
            #pragma unroll
            for (int t = 0; t < 4; ++t) o_acc[t] *= alpha;
        }
        // P = 2^(s-m); 4 consecutive keys per n -> b64 LDS writes
        float psum = 0.f;
        #pragma unroll
        for (int n = 0; n < 4; ++n) {
            bf16x4 w;
            #pragma unroll
            for (int r = 0; r < 4; ++r) {
                const float e = __builtin_amdgcn_exp2f(s[n][r] - m_r);
                psum += e;
                w[r] = (bf16_t)e;
            }
            *(bf16x4*)(pbase + swz(l16, n * 32 + lhi * 8)) = w;
        }
        l_part += psum;

        // B-fragments of P: lane = q-col l16, k = keys kk*32 + lhi*8 + j
        bf16x8 pb[2];
        #pragma unroll
        for (int kk = 0; kk < 2; ++kk)
            pb[kk] = *(const bf16x8*)(pbase + swz(l16, kk * 64 + lhi * 16));

        // ---- PV swapped: O^T = V^T P^T -> lane = q-col, d-rows ----
        __builtin_amdgcn_s_setprio(1);
        #pragma unroll
        for (int t = 0; t < 4; ++t) {
            #pragma unroll
            for (int kk = 0; kk < 2; ++kk) {
                bf16x8 vb = *(const bf16x8*)(vbase + swz(t * 16 + l16, kk * 64 + lhi * 16));
                o_acc[t] = __builtin_amdgcn_mfma_f32_16x16x32_bf16(vb, pb[kk], o_acc[t], 0, 0, 0);
            }
        }
        __builtin_amdgcn_s_setprio(0);

        // regs -> LDS for next tile; vmcnt paid HERE (after full compute phase)
        if (more) write_tile(cur ^ 1);
        cur ^= 1;
    }

    // ---- epilogue: finish l over the 4-lane lhi group, divide, vector store ----
    float l = l_part;
    l += __shfl_xor(l, 16, 64);
    l += __shfl_xor(l, 32, 64);
    const float inv = 1.f / l;
    float* op = out + (((size_t)b * Q_ + qrow) * H_ + h) * D_;
    #pragma unroll
    for (int t = 0; t < 4; ++t) {
        f32x4 res = o_acc[t];
        #pragma unroll
        for (int r = 0; r < 4; ++r) res[r] *= inv;
        *(f32x4*)(op + t * 16 + lhi * 4) = res;
    }
}

extern "C" void kernel_launch(void* const* d_in, const int* in_sizes, int n_in,
                              void* d_out, int out_size, void* d_ws, size_t ws_size,
                              hipStream_t stream) {
    const float* qs = (const float*)d_in[0];
    const float* ks = (const float*)d_in[1];
    const float* vs = (const float*)d_in[2];
    const int*   vl = (const int*)d_in[3];
    float*       out = (float*)d_out;
    dim3 grid(Q_ / 128, H_, B_);
    attn_fwd_kernel<<<grid, 512, 0, stream>>>(qs, ks, vs, vl, out);
}